// Round 2
// baseline (195.064 us; speedup 1.0000x reference)
//
#include <hip/hip_runtime.h>
#include <hip/hip_bf16.h>

#define HEADS 4
#define UNITS 64
#define IN_DIM_ 128
#define NN 512
#define TOPK 32
#define NEGV -1e9f

__device__ __forceinline__ float readlane_f(float v, int l) {
    return __int_as_float(__builtin_amdgcn_readlane(__float_as_int(v), l));
}
__device__ __forceinline__ unsigned mapu(float x) {
    unsigned b = __float_as_uint(x);
    return b ^ ((unsigned)((int)b >> 31) | 0x80000000u);
}
__device__ __forceinline__ int mbcnt64(unsigned long long m) {
    return __builtin_amdgcn_mbcnt_hi((unsigned)(m >> 32),
           __builtin_amdgcn_mbcnt_lo((unsigned)(m & 0xFFFFFFFFull), 0u));
}

// ---------------- Kernel 1: projections + transposed copy + a-dot scalars ----
__global__ __launch_bounds__(256) void gat_k1(
    const float* __restrict__ feat, const float* __restrict__ Wsrc,
    const float* __restrict__ Wdst, const float* __restrict__ a,
    float* __restrict__ hsrc, float* __restrict__ hdstT,
    float* __restrict__ As, float* __restrict__ Ad)
{
    const int bx = blockIdx.x;
    const int rb = bx & 127;         // 128 row-blocks of 32 rows (4096 rows)
    const int h  = (bx >> 7) & 3;
    const int sd = bx >> 9;          // 0 = src, 1 = dst
    const int r0 = rb * 32;
    const float* W = (sd ? Wdst : Wsrc) + h * (IN_DIM_ * UNITS);

    __shared__ float xs[32][132];    // padded: rows hit distinct banks, 16B aligned
    __shared__ float wsh[128][64];
    __shared__ float ot[32][65];

    const int tid = threadIdx.x;
    #pragma unroll
    for (int it = 0; it < 4; ++it) {
        int f4 = it * 256 + tid;
        int r = f4 >> 5, c4 = (f4 & 31) << 2;
        *(float4*)&xs[r][c4] = *(const float4*)&feat[(r0 + r) * IN_DIM_ + c4];
    }
    #pragma unroll
    for (int it = 0; it < 8; ++it) {
        int f4 = it * 256 + tid;
        int r = f4 >> 4, c4 = (f4 & 15) << 2;
        *(float4*)&wsh[r][c4] = *(const float4*)&W[r * UNITS + c4];
    }
    __syncthreads();

    const int tx = tid & 15, ty = tid >> 4;
    float acc[2][4] = {{0.f,0.f,0.f,0.f},{0.f,0.f,0.f,0.f}};
    for (int k4 = 0; k4 < 128; k4 += 4) {
        float4 x0 = *(const float4*)&xs[ty*2+0][k4];
        float4 x1 = *(const float4*)&xs[ty*2+1][k4];
        float4 w0 = *(const float4*)&wsh[k4+0][tx*4];
        float4 w1 = *(const float4*)&wsh[k4+1][tx*4];
        float4 w2 = *(const float4*)&wsh[k4+2][tx*4];
        float4 w3 = *(const float4*)&wsh[k4+3][tx*4];
#define K1STEP(xc, wq) \
        acc[0][0]=fmaf(x0.xc,wq.x,acc[0][0]); acc[0][1]=fmaf(x0.xc,wq.y,acc[0][1]); \
        acc[0][2]=fmaf(x0.xc,wq.z,acc[0][2]); acc[0][3]=fmaf(x0.xc,wq.w,acc[0][3]); \
        acc[1][0]=fmaf(x1.xc,wq.x,acc[1][0]); acc[1][1]=fmaf(x1.xc,wq.y,acc[1][1]); \
        acc[1][2]=fmaf(x1.xc,wq.z,acc[1][2]); acc[1][3]=fmaf(x1.xc,wq.w,acc[1][3]);
        K1STEP(x, w0) K1STEP(y, w1) K1STEP(z, w2) K1STEP(w, w3)
#undef K1STEP
    }
    if (sd == 0) {
        #pragma unroll
        for (int r = 0; r < 2; ++r) {
            float4 v = make_float4(acc[r][0], acc[r][1], acc[r][2], acc[r][3]);
            *(float4*)&hsrc[(h * 4096 + r0 + ty*2 + r) * UNITS + tx*4] = v;
        }
    }
    #pragma unroll
    for (int r = 0; r < 2; ++r) {
        #pragma unroll
        for (int c = 0; c < 4; ++c) ot[ty*2 + r][tx*4 + c] = acc[r][c];
    }
    __syncthreads();
    if (sd == 1) {
        const int bidx = r0 >> 9, jb0 = r0 & 511;
        #pragma unroll
        for (int it = 0; it < 8; ++it) {
            int f = it * 256 + tid;
            int u = f >> 5, jl = f & 31;
            hdstT[(((h*8 + bidx) * 64 + u) << 9) + jb0 + jl] = ot[jl][u];
        }
    }
    if (tid < 32) {
        float s = 0.f;
        for (int u = 0; u < 64; ++u) s += ot[tid][u] * a[h*64 + u];
        (sd ? Ad : As)[h * 4096 + r0 + tid] = s;
    }
}

// ---------------- Kernel 2: scores + top-k + sparsemax + sharpen + gather ----
#define K2_SMEM (131072 + 2048 + 8*72*4 + 8*72*4)   // dstT + Ad + zbuf + jbuf = 137728

__global__ __launch_bounds__(512) void gat_k2(
    const float* __restrict__ hsrc, const float* __restrict__ hdstT,
    const float* __restrict__ As_g, const float* __restrict__ Ad_g,
    const int* __restrict__ adj, const float* __restrict__ a_g,
    float* __restrict__ out)
{
    extern __shared__ char smem[];
    float* dT   = (float*)smem;              // [64][512] fp32 = 128 KB
    float* adb  = dT + 32768;                // [512]
    float* zAll = adb + 512;                 // 8 waves * 72
    int*   jAll = (int*)(zAll + 8*72);

    const int tid = threadIdx.x;
    const int w = tid >> 6, lane = tid & 63;
    float* zbuf = zAll + w * 72;
    int*   jbuf = jAll + w * 72;

    const int b    = blockIdx.x >> 5;
    const int iblk = blockIdx.x & 31;
    const int i0w  = iblk * 16 + w * 2;      // this wave's 2 rows
    const unsigned VALIDU = mapu(-5e7f);

    float outAcc[2] = {0.f, 0.f};

    for (int h = 0; h < HEADS; ++h) {
        __syncthreads();
        {
            const float4* s4 = (const float4*)(hdstT + ((h*8 + b) << 15));
            float4* d4 = (float4*)dT;
            #pragma unroll
            for (int it = 0; it < 16; ++it) d4[it*512 + tid] = s4[it*512 + tid];
            adb[tid] = Ad_g[h*4096 + b*512 + tid];
        }
        __syncthreads();

        const float aqreg = 0.05f * a_g[h*64 + lane];   // 0.4/8 * a
        const int grow0 = b*512 + i0w;
        const float sreg0 = hsrc[((h*4096 + grow0) << 6) + lane];
        const float sreg1 = hsrc[((h*4096 + grow0 + 1) << 6) + lane];
        const float Asi0 = As_g[h*4096 + grow0];
        const float Asi1 = As_g[h*4096 + grow0 + 1];

        float acc0[8] = {0,0,0,0,0,0,0,0};
        float acc1[8] = {0,0,0,0,0,0,0,0};
        #pragma unroll 8
        for (int u = 0; u < 64; ++u) {
            const float su0 = readlane_f(sreg0, u);
            const float su1 = readlane_f(sreg1, u);
            const float qu  = readlane_f(aqreg, u);
            const float4 d0 = *(const float4*)&dT[(u << 9) + (lane << 2)];
            const float4 d1 = *(const float4*)&dT[(u << 9) + 256 + (lane << 2)];
            acc0[0]=fmaf(qu,fabsf(su0+d0.x),acc0[0]); acc0[1]=fmaf(qu,fabsf(su0+d0.y),acc0[1]);
            acc0[2]=fmaf(qu,fabsf(su0+d0.z),acc0[2]); acc0[3]=fmaf(qu,fabsf(su0+d0.w),acc0[3]);
            acc0[4]=fmaf(qu,fabsf(su0+d1.x),acc0[4]); acc0[5]=fmaf(qu,fabsf(su0+d1.y),acc0[5]);
            acc0[6]=fmaf(qu,fabsf(su0+d1.z),acc0[6]); acc0[7]=fmaf(qu,fabsf(su0+d1.w),acc0[7]);
            acc1[0]=fmaf(qu,fabsf(su1+d0.x),acc1[0]); acc1[1]=fmaf(qu,fabsf(su1+d0.y),acc1[1]);
            acc1[2]=fmaf(qu,fabsf(su1+d0.z),acc1[2]); acc1[3]=fmaf(qu,fabsf(su1+d0.w),acc1[3]);
            acc1[4]=fmaf(qu,fabsf(su1+d1.x),acc1[4]); acc1[5]=fmaf(qu,fabsf(su1+d1.y),acc1[5]);
            acc1[6]=fmaf(qu,fabsf(su1+d1.z),acc1[6]); acc1[7]=fmaf(qu,fabsf(su1+d1.w),acc1[7]);
        }
        const float4 ad0 = *(const float4*)&adb[lane << 2];
        const float4 ad1 = *(const float4*)&adb[256 + (lane << 2)];

        for (int rr = 0; rr < 2; ++rr) {
            const int i = i0w + rr;
            const int grow = b*512 + i;
            const float Asi = rr ? Asi1 : Asi0;
            const float* accp = rr ? acc1 : acc0;
            const int4 av0 = *(const int4*)&adj[(grow << 9) + (lane << 2)];
            const int4 av1 = *(const int4*)&adj[(grow << 9) + 256 + (lane << 2)];
            const float adv[8] = {ad0.x,ad0.y,ad0.z,ad0.w,ad1.x,ad1.y,ad1.z,ad1.w};
            const int   avv[8] = {av0.x,av0.y,av0.z,av0.w,av1.x,av1.y,av1.z,av1.w};
            float m[8]; int jj[8];
            #pragma unroll
            for (int k = 0; k < 8; ++k) {
                int j = ((k >> 2) << 8) + (lane << 2) + (k & 3);
                jj[k] = j;
                float sc = accp[k] + 0.075f * (Asi + adv[k]);   // 0.6/8 linear part
                m[k] = (avv[k] > 0 || j == i) ? sc : NEGV;
            }
            unsigned ux[8];
            #pragma unroll
            for (int k = 0; k < 8; ++k) ux[k] = mapu(m[k]);
            // exact 32nd-largest via radix descent on monotone uint keys
            unsigned prefix = 0u;
            for (int bit = 31; bit >= 0; --bit) {
                unsigned T = prefix | (1u << bit);
                int c0 = 0;
                #pragma unroll
                for (int k = 0; k < 8; ++k) c0 += __popcll(__ballot(ux[k] >= T));
                if (c0 >= TOPK) prefix = T;
            }
            // compact survivors (score >= kth AND valid) into per-wave LDS
            int cnt = 0;
            #pragma unroll
            for (int k = 0; k < 8; ++k) {
                bool sv = (ux[k] >= prefix) && (ux[k] > VALIDU);
                unsigned long long mm = __ballot(sv);
                if (sv) {
                    int pos = cnt + mbcnt64(mm);
                    if (pos < 64) { zbuf[pos] = 2.f * m[k]; jbuf[pos] = jj[k]; }
                }
                cnt += __popcll(mm);
            }
            if (cnt > 64) cnt = 64;
            if (lane < 4) { zbuf[cnt + lane] = -1e30f; jbuf[cnt + lane] = 0; }
            const int nt4 = (cnt + 3) >> 2;
            // zmax (uniform scan of compacted survivors)
            float zmax = -1e30f;
            for (int t4 = 0; t4 < nt4; ++t4) {
                float4 q = *(const float4*)&zbuf[t4 << 2];
                zmax = fmaxf(zmax, fmaxf(fmaxf(q.x, q.y), fmaxf(q.z, q.w)));
            }
            // bracket tau: 3 rounds of 64 lane-candidates -> width 64^-3
            float lo = zmax - 1.0f, width = 1.0f;
            for (int r3 = 0; r3 < 3; ++r3) {
                float step = width * 0.015625f;
                float tc = lo + step * (float)(lane + 1);
                float f = 0.f;
                for (int t4 = 0; t4 < nt4; ++t4) {
                    float4 q = *(const float4*)&zbuf[t4 << 2];
                    f += fmaxf(q.x - tc, 0.f) + fmaxf(q.y - tc, 0.f)
                       + fmaxf(q.z - tc, 0.f) + fmaxf(q.w - tc, 0.f);
                }
                int p = __popcll(__ballot(f >= 1.0f));
                lo += step * (float)p;
                width = step;
            }
            const float taum = lo + 0.5f * width;
            // exact closed-form tau on stable support
            float S = 0.f; int ks = 0;
            for (int t4 = 0; t4 < nt4; ++t4) {
                float4 q = *(const float4*)&zbuf[t4 << 2];
                if (q.x > taum) { S += q.x; ++ks; }
                if (q.y > taum) { S += q.y; ++ks; }
                if (q.z > taum) { S += q.z; ++ks; }
                if (q.w > taum) { S += q.w; ++ks; }
            }
            if (ks == 0) { ks = 1; S = zmax; }
            const float tau = (S - 1.0f) / (float)ks;
            // sharpen + denom
            float pl = 0.f;
            if (lane < cnt) {
                float wv = fmaxf(zbuf[lane] - tau, 0.f) + 1e-9f;
                pl = wv * wv;
            }
            float dsum = pl;
            #pragma unroll
            for (int d = 1; d < 64; d <<= 1) dsum += __shfl_xor(dsum, d, 64);
            const float denom = dsum + 1e-9f + (float)(512 - cnt) * 1e-18f;
            const float rd = 1.0f / denom;
            // gather: out_u += w_t * h_src[j_t][u]
            float oa = 0.f;
            #pragma unroll
            for (int t = 0; t < TOPK; ++t) {
                float zt = zbuf[t];
                int jt = jbuf[t] & 511;
                float wv = fmaxf(zt - tau, 0.f) + 1e-9f;
                wv = wv * wv * rd;
                if (t >= cnt) wv = 0.f;
                oa = fmaf(wv, hsrc[((h*4096 + b*512 + jt) << 6) + lane], oa);
            }
            for (int t = TOPK; t < cnt; ++t) {   // rare tie overflow
                float zt = zbuf[t];
                int jt = jbuf[t] & 511;
                float wv = fmaxf(zt - tau, 0.f) + 1e-9f;
                wv = wv * wv * rd;
                oa = fmaf(wv, hsrc[((h*4096 + b*512 + jt) << 6) + lane], oa);
            }
            outAcc[rr] += oa;
        }
    }
    #pragma unroll
    for (int rr = 0; rr < 2; ++rr) {
        int i = i0w + rr;
        out[((b*512 + i) << 6) + lane] = 0.25f * outAcc[rr];
    }
}

extern "C" void kernel_launch(void* const* d_in, const int* in_sizes, int n_in,
                              void* d_out, int out_size, void* d_ws, size_t ws_size,
                              hipStream_t stream) {
    const float* feat = (const float*)d_in[0];
    const int*   adj  = (const int*)d_in[1];
    const float* Wsrc = (const float*)d_in[2];
    const float* Wdst = (const float*)d_in[3];
    const float* a    = (const float*)d_in[4];
    float* out = (float*)d_out;
    float* ws  = (float*)d_ws;
    float* hsrc  = ws;                 // 4*4096*64   = 1048576 floats
    float* hdstT = ws + 1048576;       // 4*8*64*512  = 1048576 floats
    float* As    = ws + 2097152;       // 4*4096
    float* Ad    = ws + 2113536;       // 4*4096

    hipFuncSetAttribute(reinterpret_cast<const void*>(gat_k2),
                        hipFuncAttributeMaxDynamicSharedMemorySize, K2_SMEM);
    gat_k1<<<1024, 256, 0, stream>>>(feat, Wsrc, Wdst, a, hsrc, hdstT, As, Ad);
    gat_k2<<<256, 512, K2_SMEM, stream>>>(hsrc, hdstT, As, Ad, adj, a, out);
}

// Round 9
// 175.675 us; speedup vs baseline: 1.1104x; 1.1104x over previous
//
#include <hip/hip_runtime.h>
#include <hip/hip_bf16.h>

#define HEADS 4
#define UNITS 64
#define IN_DIM_ 128
#define NN 512
#define TOPK 32
#define NEGV -1e9f

__device__ __forceinline__ float readlane_f(float v, int l) {
    return __int_as_float(__builtin_amdgcn_readlane(__float_as_int(v), l));
}
__device__ __forceinline__ unsigned mapu(float x) {
    unsigned b = __float_as_uint(x);
    return b ^ ((unsigned)((int)b >> 31) | 0x80000000u);
}
__device__ __forceinline__ int mbcnt64(unsigned long long m) {
    return __builtin_amdgcn_mbcnt_hi((unsigned)(m >> 32),
           __builtin_amdgcn_mbcnt_lo((unsigned)(m & 0xFFFFFFFFull), 0u));
}

// ---------------- Kernel 1: projections + transposed copy + a-dot scalars ----
__global__ __launch_bounds__(256) void gat_k1(
    const float* __restrict__ feat, const float* __restrict__ Wsrc,
    const float* __restrict__ Wdst, const float* __restrict__ a,
    float* __restrict__ hsrc, float* __restrict__ hdstT,
    float* __restrict__ As, float* __restrict__ Ad)
{
    const int bx = blockIdx.x;
    const int rb = bx & 127;         // 128 row-blocks of 32 rows (4096 rows)
    const int h  = (bx >> 7) & 3;
    const int sd = bx >> 9;          // 0 = src, 1 = dst
    const int r0 = rb * 32;
    const float* W = (sd ? Wdst : Wsrc) + h * (IN_DIM_ * UNITS);

    __shared__ float xs[32][132];
    __shared__ float wsh[128][64];
    __shared__ float ot[32][65];

    const int tid = threadIdx.x;
    #pragma unroll
    for (int it = 0; it < 4; ++it) {
        int f4 = it * 256 + tid;
        int r = f4 >> 5, c4 = (f4 & 31) << 2;
        *(float4*)&xs[r][c4] = *(const float4*)&feat[(r0 + r) * IN_DIM_ + c4];
    }
    #pragma unroll
    for (int it = 0; it < 8; ++it) {
        int f4 = it * 256 + tid;
        int r = f4 >> 4, c4 = (f4 & 15) << 2;
        *(float4*)&wsh[r][c4] = *(const float4*)&W[r * UNITS + c4];
    }
    __syncthreads();

    const int tx = tid & 15, ty = tid >> 4;
    float acc[2][4] = {{0.f,0.f,0.f,0.f},{0.f,0.f,0.f,0.f}};
    for (int k4 = 0; k4 < 128; k4 += 4) {
        float4 x0 = *(const float4*)&xs[ty*2+0][k4];
        float4 x1 = *(const float4*)&xs[ty*2+1][k4];
        float4 w0 = *(const float4*)&wsh[k4+0][tx*4];
        float4 w1 = *(const float4*)&wsh[k4+1][tx*4];
        float4 w2 = *(const float4*)&wsh[k4+2][tx*4];
        float4 w3 = *(const float4*)&wsh[k4+3][tx*4];
#define K1STEP(xc, wq) \
        acc[0][0]=fmaf(x0.xc,wq.x,acc[0][0]); acc[0][1]=fmaf(x0.xc,wq.y,acc[0][1]); \
        acc[0][2]=fmaf(x0.xc,wq.z,acc[0][2]); acc[0][3]=fmaf(x0.xc,wq.w,acc[0][3]); \
        acc[1][0]=fmaf(x1.xc,wq.x,acc[1][0]); acc[1][1]=fmaf(x1.xc,wq.y,acc[1][1]); \
        acc[1][2]=fmaf(x1.xc,wq.z,acc[1][2]); acc[1][3]=fmaf(x1.xc,wq.w,acc[1][3]);
        K1STEP(x, w0) K1STEP(y, w1) K1STEP(z, w2) K1STEP(w, w3)
#undef K1STEP
    }
    if (sd == 0) {
        #pragma unroll
        for (int r = 0; r < 2; ++r) {
            float4 v = make_float4(acc[r][0], acc[r][1], acc[r][2], acc[r][3]);
            *(float4*)&hsrc[(h * 4096 + r0 + ty*2 + r) * UNITS + tx*4] = v;
        }
    }
    #pragma unroll
    for (int r = 0; r < 2; ++r) {
        #pragma unroll
        for (int c = 0; c < 4; ++c) ot[ty*2 + r][tx*4 + c] = acc[r][c];
    }
    __syncthreads();
    if (sd == 1) {
        const int bidx = r0 >> 9, jb0 = r0 & 511;
        #pragma unroll
        for (int it = 0; it < 8; ++it) {
            int f = it * 256 + tid;
            int u = f >> 5, jl = f & 31;
            hdstT[(((h*8 + bidx) * 64 + u) << 9) + jb0 + jl] = ot[jl][u];
        }
    }
    if (tid < 32) {
        float s = 0.f;
        for (int u = 0; u < 64; ++u) s += ot[tid][u] * a[h*64 + u];
        (sd ? Ad : As)[h * 4096 + r0 + tid] = s;
    }
}

// ---- Kernel 2: wave = (row-pair, head). No staging, no barriers, L2-direct. ----
__global__ __launch_bounds__(256, 8) void gat_k2(
    const float* __restrict__ hsrc, const float* __restrict__ hdstT,
    const float* __restrict__ As_g, const float* __restrict__ Ad_g,
    const int* __restrict__ adj, const float* __restrict__ a_g,
    float* __restrict__ out)
{
    __shared__ float zAll[4 * 72];
    __shared__ int   jAll[4 * 72];

    const int tid = threadIdx.x;
    const int w = tid >> 6, lane = tid & 63;
    float* zbuf = zAll + w * 72;
    int*   jbuf = jAll + w * 72;

    // XCD-bijective swizzle: 2048 blocks, each XCD gets 256 consecutive work-ids
    const int bid = blockIdx.x;
    const int swz = (bid & 7) * 256 + (bid >> 3);
    const int wid = swz * 4 + w;          // 0..8191
    const int slice = wid >> 8;           // h*8 + b   (32 slices)
    const int rp    = wid & 255;          // row-pair within slice
    const int h = slice >> 3, b = slice & 7;
    const int i0 = rp * 2;
    const unsigned VALIDU = mapu(-5e7f);

    const float* dbase = hdstT + (slice << 15);    // [64][512] fp32 slice

    const float aqreg = 0.05f * a_g[h*64 + lane];  // 0.4/8 * a
    const int grow0 = b*512 + i0;
    const float sreg0 = hsrc[((h*4096 + grow0) << 6) + lane];
    const float sreg1 = hsrc[((h*4096 + grow0 + 1) << 6) + lane];
    const float Asi0 = As_g[h*4096 + grow0];
    const float Asi1 = As_g[h*4096 + grow0 + 1];

    float acc0[8] = {0,0,0,0,0,0,0,0};
    float acc1[8] = {0,0,0,0,0,0,0,0};
    #pragma unroll 8
    for (int u = 0; u < 64; ++u) {
        const float4 d0 = *(const float4*)&dbase[(u << 9) + (lane << 2)];
        const float4 d1 = *(const float4*)&dbase[(u << 9) + 256 + (lane << 2)];
        const float su0 = readlane_f(sreg0, u);
        const float su1 = readlane_f(sreg1, u);
        const float qu  = readlane_f(aqreg, u);
        acc0[0]=fmaf(qu,fabsf(su0+d0.x),acc0[0]); acc0[1]=fmaf(qu,fabsf(su0+d0.y),acc0[1]);
        acc0[2]=fmaf(qu,fabsf(su0+d0.z),acc0[2]); acc0[3]=fmaf(qu,fabsf(su0+d0.w),acc0[3]);
        acc0[4]=fmaf(qu,fabsf(su0+d1.x),acc0[4]); acc0[5]=fmaf(qu,fabsf(su0+d1.y),acc0[5]);
        acc0[6]=fmaf(qu,fabsf(su0+d1.z),acc0[6]); acc0[7]=fmaf(qu,fabsf(su0+d1.w),acc0[7]);
        acc1[0]=fmaf(qu,fabsf(su1+d0.x),acc1[0]); acc1[1]=fmaf(qu,fabsf(su1+d0.y),acc1[1]);
        acc1[2]=fmaf(qu,fabsf(su1+d0.z),acc1[2]); acc1[3]=fmaf(qu,fabsf(su1+d0.w),acc1[3]);
        acc1[4]=fmaf(qu,fabsf(su1+d1.x),acc1[4]); acc1[5]=fmaf(qu,fabsf(su1+d1.y),acc1[5]);
        acc1[6]=fmaf(qu,fabsf(su1+d1.z),acc1[6]); acc1[7]=fmaf(qu,fabsf(su1+d1.w),acc1[7]);
    }
    const float4 ad0 = *(const float4*)&Ad_g[h*4096 + b*512 + (lane << 2)];
    const float4 ad1 = *(const float4*)&Ad_g[h*4096 + b*512 + 256 + (lane << 2)];

    float outAcc[2];
    for (int rr = 0; rr < 2; ++rr) {
        const int i = i0 + rr;
        const int grow = b*512 + i;
        const float Asi = rr ? Asi1 : Asi0;
        const float* accp = rr ? acc1 : acc0;
        const int4 av0 = *(const int4*)&adj[(grow << 9) + (lane << 2)];
        const int4 av1 = *(const int4*)&adj[(grow << 9) + 256 + (lane << 2)];
        const float adv[8] = {ad0.x,ad0.y,ad0.z,ad0.w,ad1.x,ad1.y,ad1.z,ad1.w};
        const int   avv[8] = {av0.x,av0.y,av0.z,av0.w,av1.x,av1.y,av1.z,av1.w};
        float m[8]; int jj[8];
        #pragma unroll
        for (int k = 0; k < 8; ++k) {
            int j = ((k >> 2) << 8) + (lane << 2) + (k & 3);
            jj[k] = j;
            float sc = accp[k] + 0.075f * (Asi + adv[k]);   // 0.6/8 linear part
            m[k] = (avv[k] > 0 || j == i) ? sc : NEGV;
        }
        unsigned ux[8];
        #pragma unroll
        for (int k = 0; k < 8; ++k) ux[k] = mapu(m[k]);
        // exact 32nd-largest via radix descent; early exit when count hits exactly 32
        unsigned prefix = 0u;
        for (int bit = 31; bit >= 0; --bit) {
            unsigned T = prefix | (1u << bit);
            int c0 = 0;
            #pragma unroll
            for (int k = 0; k < 8; ++k) c0 += __popcll(__ballot(ux[k] >= T));
            if (c0 >= TOPK) {
                prefix = T;
                if (c0 == TOPK) break;    // set {ux>=T} == set {ux>=kth}
            }
        }
        // compact survivors (score >= kth AND valid) into per-wave LDS
        int cnt = 0;
        #pragma unroll
        for (int k = 0; k < 8; ++k) {
            bool sv = (ux[k] >= prefix) && (ux[k] > VALIDU);
            unsigned long long mm = __ballot(sv);
            if (sv) {
                int pos = cnt + mbcnt64(mm);
                if (pos < 64) { zbuf[pos] = 2.f * m[k]; jbuf[pos] = jj[k]; }
            }
            cnt += __popcll(mm);
        }
        if (cnt > 64) cnt = 64;
        if (lane < 4) { zbuf[cnt + lane] = -1e30f; jbuf[cnt + lane] = 0; }
        const int nt4 = (cnt + 3) >> 2;
        float zmax = -1e30f;
        for (int t4 = 0; t4 < nt4; ++t4) {
            float4 q = *(const float4*)&zbuf[t4 << 2];
            zmax = fmaxf(zmax, fmaxf(fmaxf(q.x, q.y), fmaxf(q.z, q.w)));
        }
        // bracket tau: 3 rounds of 64 lane-candidates
        float lo = zmax - 1.0f, width = 1.0f;
        for (int r3 = 0; r3 < 3; ++r3) {
            float step = width * 0.015625f;
            float tc = lo + step * (float)(lane + 1);
            float f = 0.f;
            for (int t4 = 0; t4 < nt4; ++t4) {
                float4 q = *(const float4*)&zbuf[t4 << 2];
                f += fmaxf(q.x - tc, 0.f) + fmaxf(q.y - tc, 0.f)
                   + fmaxf(q.z - tc, 0.f) + fmaxf(q.w - tc, 0.f);
            }
            int p = __popcll(__ballot(f >= 1.0f));
            lo += step * (float)p;
            width = step;
        }
        const float taum = lo + 0.5f * width;
        float S = 0.f; int ks = 0;
        for (int t4 = 0; t4 < nt4; ++t4) {
            float4 q = *(const float4*)&zbuf[t4 << 2];
            if (q.x > taum) { S += q.x; ++ks; }
            if (q.y > taum) { S += q.y; ++ks; }
            if (q.z > taum) { S += q.z; ++ks; }
            if (q.w > taum) { S += q.w; ++ks; }
        }
        if (ks == 0) { ks = 1; S = zmax; }
        const float tau = (S - 1.0f) / (float)ks;
        // sharpen + denom
        float pl = 0.f;
        if (lane < cnt) {
            float wv = fmaxf(zbuf[lane] - tau, 0.f) + 1e-9f;
            pl = wv * wv;
        }
        float dsum = pl;
        #pragma unroll
        for (int d = 1; d < 64; d <<= 1) dsum += __shfl_xor(dsum, d, 64);
        const float denom = dsum + 1e-9f + (float)(512 - cnt) * 1e-18f;
        const float rd = 1.0f / denom;
        // gather
        float oa = 0.f;
        #pragma unroll
        for (int t = 0; t < TOPK; ++t) {
            float zt = zbuf[t];
            int jt = jbuf[t] & 511;
            float wv = fmaxf(zt - tau, 0.f) + 1e-9f;
            wv = wv * wv * rd;
            if (t >= cnt) wv = 0.f;
            oa = fmaf(wv, hsrc[((h*4096 + b*512 + jt) << 6) + lane], oa);
        }
        for (int t = TOPK; t < cnt; ++t) {
            float zt = zbuf[t];
            int jt = jbuf[t] & 511;
            float wv = fmaxf(zt - tau, 0.f) + 1e-9f;
            wv = wv * wv * rd;
            oa = fmaf(wv, hsrc[((h*4096 + b*512 + jt) << 6) + lane], oa);
        }
        outAcc[rr] = oa;
    }
    #pragma unroll
    for (int rr = 0; rr < 2; ++rr) {
        int i = i0 + rr;
        atomicAdd(&out[((b*512 + i) << 6) + lane], 0.25f * outAcc[rr]);
    }
}

extern "C" void kernel_launch(void* const* d_in, const int* in_sizes, int n_in,
                              void* d_out, int out_size, void* d_ws, size_t ws_size,
                              hipStream_t stream) {
    const float* feat = (const float*)d_in[0];
    const int*   adj  = (const int*)d_in[1];
    const float* Wsrc = (const float*)d_in[2];
    const float* Wdst = (const float*)d_in[3];
    const float* a    = (const float*)d_in[4];
    float* out = (float*)d_out;
    float* ws  = (float*)d_ws;
    float* hsrc  = ws;                 // 4*4096*64   = 1048576 floats
    float* hdstT = ws + 1048576;       // 4*8*64*512  = 1048576 floats
    float* As    = ws + 2097152;       // 4*4096
    float* Ad    = ws + 2113536;       // 4*4096

    hipMemsetAsync(d_out, 0, (size_t)out_size * sizeof(float), stream);
    gat_k1<<<1024, 256, 0, stream>>>(feat, Wsrc, Wdst, a, hsrc, hdstT, As, Ad);
    gat_k2<<<2048, 256, 0, stream>>>(hsrc, hdstT, As, Ad, adj, a, out);
}

// Round 10
// 153.549 us; speedup vs baseline: 1.2704x; 1.1441x over previous
//
#include <hip/hip_runtime.h>
#include <hip/hip_bf16.h>

#define HEADS 4
#define UNITS 64
#define IN_DIM_ 128
#define NN 512
#define TOPK 32
#define NEGV -1e9f

__device__ __forceinline__ float readlane_f(float v, int l) {
    return __int_as_float(__builtin_amdgcn_readlane(__float_as_int(v), l));
}
__device__ __forceinline__ unsigned mapu(float x) {
    unsigned b = __float_as_uint(x);
    return b ^ ((unsigned)((int)b >> 31) | 0x80000000u);
}
__device__ __forceinline__ int mbcnt64(unsigned long long m) {
    return __builtin_amdgcn_mbcnt_hi((unsigned)(m >> 32),
           __builtin_amdgcn_mbcnt_lo((unsigned)(m & 0xFFFFFFFFull), 0u));
}

// -------- Kernel 1: projections + transposed copy + a-dot scalars ----------
// W read direct from L1/L2 (no LDS staging): LDS 58->25 KB, 2->4+ blocks/CU.
__global__ __launch_bounds__(256) void gat_k1(
    const float* __restrict__ feat, const float* __restrict__ Wsrc,
    const float* __restrict__ Wdst, const float* __restrict__ a,
    float* __restrict__ hsrc, float* __restrict__ hdstT,
    float* __restrict__ As, float* __restrict__ Ad)
{
    const int bx = blockIdx.x;
    const int rb = bx & 127;         // 128 row-blocks of 32 rows (4096 rows)
    const int h  = (bx >> 7) & 3;
    const int sd = bx >> 9;          // 0 = src, 1 = dst
    const int r0 = rb * 32;
    const float* W = (sd ? Wdst : Wsrc) + h * (IN_DIM_ * UNITS);

    __shared__ float xs[32][132];
    __shared__ float ot[32][65];

    const int tid = threadIdx.x;
    #pragma unroll
    for (int it = 0; it < 4; ++it) {
        int f4 = it * 256 + tid;
        int r = f4 >> 5, c4 = (f4 & 31) << 2;
        *(float4*)&xs[r][c4] = *(const float4*)&feat[(r0 + r) * IN_DIM_ + c4];
    }
    __syncthreads();

    const int tx = tid & 15, ty = tid >> 4;
    float acc[2][4] = {{0.f,0.f,0.f,0.f},{0.f,0.f,0.f,0.f}};
    for (int k4 = 0; k4 < 128; k4 += 4) {
        float4 x0 = *(const float4*)&xs[ty*2+0][k4];
        float4 x1 = *(const float4*)&xs[ty*2+1][k4];
        float4 w0 = *(const float4*)&W[(k4+0) * UNITS + tx*4];
        float4 w1 = *(const float4*)&W[(k4+1) * UNITS + tx*4];
        float4 w2 = *(const float4*)&W[(k4+2) * UNITS + tx*4];
        float4 w3 = *(const float4*)&W[(k4+3) * UNITS + tx*4];
#define K1STEP(xc, wq) \
        acc[0][0]=fmaf(x0.xc,wq.x,acc[0][0]); acc[0][1]=fmaf(x0.xc,wq.y,acc[0][1]); \
        acc[0][2]=fmaf(x0.xc,wq.z,acc[0][2]); acc[0][3]=fmaf(x0.xc,wq.w,acc[0][3]); \
        acc[1][0]=fmaf(x1.xc,wq.x,acc[1][0]); acc[1][1]=fmaf(x1.xc,wq.y,acc[1][1]); \
        acc[1][2]=fmaf(x1.xc,wq.z,acc[1][2]); acc[1][3]=fmaf(x1.xc,wq.w,acc[1][3]);
        K1STEP(x, w0) K1STEP(y, w1) K1STEP(z, w2) K1STEP(w, w3)
#undef K1STEP
    }
    if (sd == 0) {
        #pragma unroll
        for (int r = 0; r < 2; ++r) {
            float4 v = make_float4(acc[r][0], acc[r][1], acc[r][2], acc[r][3]);
            *(float4*)&hsrc[(h * 4096 + r0 + ty*2 + r) * UNITS + tx*4] = v;
        }
    }
    #pragma unroll
    for (int r = 0; r < 2; ++r) {
        #pragma unroll
        for (int c = 0; c < 4; ++c) ot[ty*2 + r][tx*4 + c] = acc[r][c];
    }
    __syncthreads();
    if (sd == 1) {
        const int bidx = r0 >> 9, jb0 = r0 & 511;
        #pragma unroll
        for (int it = 0; it < 8; ++it) {
            int f = it * 256 + tid;
            int u = f >> 5, jl = f & 31;
            hdstT[(((h*8 + bidx) * 64 + u) << 9) + jb0 + jl] = ot[jl][u];
        }
    }
    if (tid < 32) {
        float s = 0.f;
        for (int u = 0; u < 64; ++u) s += ot[tid][u] * a[h*64 + u];
        (sd ? Ad : As)[h * 4096 + r0 + tid] = s;
    }
}

// ---- Kernel 2: wave = (row-pair, head). L2-direct scores; Michelot tau;
// ---- register-resident gather with readlane broadcast. ----
__global__ __launch_bounds__(256, 8) void gat_k2(
    const float* __restrict__ hsrc, const float* __restrict__ hdstT,
    const float* __restrict__ As_g, const float* __restrict__ Ad_g,
    const int* __restrict__ adj, const float* __restrict__ a_g,
    float* __restrict__ out)
{
    __shared__ float zAll[4 * 72];
    __shared__ int   jAll[4 * 72];

    const int tid = threadIdx.x;
    const int w = tid >> 6, lane = tid & 63;
    float* zbuf = zAll + w * 72;
    int*   jbuf = jAll + w * 72;

    // XCD-bijective swizzle: 2048 blocks, each XCD gets 256 consecutive work-ids
    const int bid = blockIdx.x;
    const int swz = (bid & 7) * 256 + (bid >> 3);
    const int wid = swz * 4 + w;          // 0..8191
    const int slice = wid >> 8;           // h*8 + b   (32 slices)
    const int rp    = wid & 255;          // row-pair within slice
    const int h = slice >> 3, b = slice & 7;
    const int i0 = rp * 2;
    const unsigned VALIDU = mapu(-5e7f);

    const float* dbase = hdstT + (slice << 15);    // [64][512] fp32 slice

    const float aqreg = 0.05f * a_g[h*64 + lane];  // 0.4/8 * a
    const int grow0 = b*512 + i0;
    const float sreg0 = hsrc[((h*4096 + grow0) << 6) + lane];
    const float sreg1 = hsrc[((h*4096 + grow0 + 1) << 6) + lane];
    const float Asi0 = As_g[h*4096 + grow0];
    const float Asi1 = As_g[h*4096 + grow0 + 1];

    float acc0[8] = {0,0,0,0,0,0,0,0};
    float acc1[8] = {0,0,0,0,0,0,0,0};
    #pragma unroll 8
    for (int u = 0; u < 64; ++u) {
        const float4 d0 = *(const float4*)&dbase[(u << 9) + (lane << 2)];
        const float4 d1 = *(const float4*)&dbase[(u << 9) + 256 + (lane << 2)];
        const float su0 = readlane_f(sreg0, u);
        const float su1 = readlane_f(sreg1, u);
        const float qu  = readlane_f(aqreg, u);
        acc0[0]=fmaf(qu,fabsf(su0+d0.x),acc0[0]); acc0[1]=fmaf(qu,fabsf(su0+d0.y),acc0[1]);
        acc0[2]=fmaf(qu,fabsf(su0+d0.z),acc0[2]); acc0[3]=fmaf(qu,fabsf(su0+d0.w),acc0[3]);
        acc0[4]=fmaf(qu,fabsf(su0+d1.x),acc0[4]); acc0[5]=fmaf(qu,fabsf(su0+d1.y),acc0[5]);
        acc0[6]=fmaf(qu,fabsf(su0+d1.z),acc0[6]); acc0[7]=fmaf(qu,fabsf(su0+d1.w),acc0[7]);
        acc1[0]=fmaf(qu,fabsf(su1+d0.x),acc1[0]); acc1[1]=fmaf(qu,fabsf(su1+d0.y),acc1[1]);
        acc1[2]=fmaf(qu,fabsf(su1+d0.z),acc1[2]); acc1[3]=fmaf(qu,fabsf(su1+d0.w),acc1[3]);
        acc1[4]=fmaf(qu,fabsf(su1+d1.x),acc1[4]); acc1[5]=fmaf(qu,fabsf(su1+d1.y),acc1[5]);
        acc1[6]=fmaf(qu,fabsf(su1+d1.z),acc1[6]); acc1[7]=fmaf(qu,fabsf(su1+d1.w),acc1[7]);
    }
    const float4 ad0 = *(const float4*)&Ad_g[h*4096 + b*512 + (lane << 2)];
    const float4 ad1 = *(const float4*)&Ad_g[h*4096 + b*512 + 256 + (lane << 2)];

    float outAcc[2];
    for (int rr = 0; rr < 2; ++rr) {
        const int i = i0 + rr;
        const int grow = b*512 + i;
        const float Asi = rr ? Asi1 : Asi0;
        const float* accp = rr ? acc1 : acc0;
        const int4 av0 = *(const int4*)&adj[(grow << 9) + (lane << 2)];
        const int4 av1 = *(const int4*)&adj[(grow << 9) + 256 + (lane << 2)];
        const float adv[8] = {ad0.x,ad0.y,ad0.z,ad0.w,ad1.x,ad1.y,ad1.z,ad1.w};
        const int   avv[8] = {av0.x,av0.y,av0.z,av0.w,av1.x,av1.y,av1.z,av1.w};
        float m[8]; int jj[8];
        #pragma unroll
        for (int k = 0; k < 8; ++k) {
            int j = ((k >> 2) << 8) + (lane << 2) + (k & 3);
            jj[k] = j;
            float sc = accp[k] + 0.075f * (Asi + adv[k]);   // 0.6/8 linear part
            m[k] = (avv[k] > 0 || j == i) ? sc : NEGV;
        }
        unsigned ux[8];
        #pragma unroll
        for (int k = 0; k < 8; ++k) ux[k] = mapu(m[k]);
        // exact 32nd-largest via radix descent; early exit when count hits exactly 32
        unsigned prefix = 0u;
        for (int bit = 31; bit >= 0; --bit) {
            unsigned T = prefix | (1u << bit);
            int c0 = 0;
            #pragma unroll
            for (int k = 0; k < 8; ++k) c0 += __popcll(__ballot(ux[k] >= T));
            if (c0 >= TOPK) {
                prefix = T;
                if (c0 == TOPK) break;    // set {ux>=T} == set {ux>=kth}
            }
        }
        // compact survivors (score >= kth AND valid) into per-wave LDS
        int cnt = 0;
        #pragma unroll
        for (int k = 0; k < 8; ++k) {
            bool sv = (ux[k] >= prefix) && (ux[k] > VALIDU);
            unsigned long long mm = __ballot(sv);
            if (sv) {
                int pos = cnt + mbcnt64(mm);
                if (pos < 64) { zbuf[pos] = 2.f * m[k]; jbuf[pos] = jj[k]; }
            }
            cnt += __popcll(mm);
        }
        if (cnt > 64) cnt = 64;
        if (lane < 4) { zbuf[cnt + lane] = -1e30f; jbuf[cnt + lane] = 0; }
        // per-lane survivor registers
        float zl = zbuf[lane];
        int   jl = jbuf[lane] & 511;
        bool act = (lane < cnt);
        if (!act) { zl = 0.f; jl = 0; }
        // Michelot fixed-point: exact sparsemax tau (support only shrinks)
        float tau;
        unsigned long long am = __ballot(act);
        bool cur = act;
        for (;;) {
            float s = cur ? zl : 0.f;
            #pragma unroll
            for (int d = 1; d < 64; d <<= 1) s += __shfl_xor(s, d, 64);
            const int kk = __popcll(am);
            tau = (s - 1.0f) / (float)kk;
            bool na = cur && (zl > tau);
            unsigned long long nm = __ballot(na);
            if (nm == am || nm == 0ull) break;
            am = nm; cur = na;
        }
        // sharpen + denom (per-lane)
        float wv = fmaxf(zl - tau, 0.f) + 1e-9f;
        float pl = (lane < cnt) ? wv * wv : 0.f;
        float dsum = pl;
        #pragma unroll
        for (int d = 1; d < 64; d <<= 1) dsum += __shfl_xor(dsum, d, 64);
        const float rd = 1.0f / (dsum + 1e-9f + (float)(512 - cnt) * 1e-18f);
        const float wlane = pl * rd;           // final weight held in lane t
        // gather: broadcast (w_t, j_t) from lane t; loads pipeline freely
        const float* hb = hsrc + ((h*4096 + b*512) << 6) + lane;
        float oa = 0.f;
        #pragma unroll
        for (int t = 0; t < TOPK; ++t) {
            float wt = readlane_f(wlane, t);
            int   jt = __builtin_amdgcn_readlane(jl, t);
            oa = fmaf(wt, hb[jt << 6], oa);
        }
        for (int t = TOPK; t < cnt; ++t) {     // rare tie overflow
            float wt = readlane_f(wlane, t);
            int   jt = __builtin_amdgcn_readlane(jl, t);
            oa = fmaf(wt, hb[jt << 6], oa);
        }
        outAcc[rr] = oa;
    }
    #pragma unroll
    for (int rr = 0; rr < 2; ++rr) {
        int i = i0 + rr;
        atomicAdd(&out[((b*512 + i) << 6) + lane], 0.25f * outAcc[rr]);
    }
}

extern "C" void kernel_launch(void* const* d_in, const int* in_sizes, int n_in,
                              void* d_out, int out_size, void* d_ws, size_t ws_size,
                              hipStream_t stream) {
    const float* feat = (const float*)d_in[0];
    const int*   adj  = (const int*)d_in[1];
    const float* Wsrc = (const float*)d_in[2];
    const float* Wdst = (const float*)d_in[3];
    const float* a    = (const float*)d_in[4];
    float* out = (float*)d_out;
    float* ws  = (float*)d_ws;
    float* hsrc  = ws;                 // 4*4096*64   = 1048576 floats
    float* hdstT = ws + 1048576;       // 4*8*64*512  = 1048576 floats
    float* As    = ws + 2097152;       // 4*4096
    float* Ad    = ws + 2113536;       // 4*4096

    hipMemsetAsync(d_out, 0, (size_t)out_size * sizeof(float), stream);
    gat_k1<<<1024, 256, 0, stream>>>(feat, Wsrc, Wdst, a, hsrc, hdstT, As, Ad);
    gat_k2<<<2048, 256, 0, stream>>>(hsrc, hdstT, As, Ad, adj, a, out);
}

// Round 13
// 152.946 us; speedup vs baseline: 1.2754x; 1.0039x over previous
//
#include <hip/hip_runtime.h>
#include <hip/hip_bf16.h>

#define HEADS 4
#define UNITS 64
#define IN_DIM_ 128
#define NN 512
#define TOPK 32
#define NEGV -1e9f

__device__ __forceinline__ float readlane_f(float v, int l) {
    return __int_as_float(__builtin_amdgcn_readlane(__float_as_int(v), l));
}
__device__ __forceinline__ unsigned mapu(float x) {
    unsigned b = __float_as_uint(x);
    return b ^ ((unsigned)((int)b >> 31) | 0x80000000u);
}
__device__ __forceinline__ float unmapu(unsigned u) {
    unsigned b = ((int)u < 0) ? (u ^ 0x80000000u) : ~u;
    return __uint_as_float(b);
}
__device__ __forceinline__ int mbcnt64(unsigned long long m) {
    return __builtin_amdgcn_mbcnt_hi((unsigned)(m >> 32),
           __builtin_amdgcn_mbcnt_lo((unsigned)(m & 0xFFFFFFFFull), 0u));
}

// -------- Kernel 1: projections + transposed copy + a-dot scalars ----------
// W direct from L1/L2; a-dot fully parallel from registers (no serial tail).
__global__ __launch_bounds__(256) void gat_k1(
    const float* __restrict__ feat, const float* __restrict__ Wsrc,
    const float* __restrict__ Wdst, const float* __restrict__ a,
    float* __restrict__ hsrc, float* __restrict__ hdstT,
    float* __restrict__ As, float* __restrict__ Ad)
{
    const int bx = blockIdx.x;
    const int rb = bx & 127;         // 128 row-blocks of 32 rows (4096 rows)
    const int h  = (bx >> 7) & 3;
    const int sd = bx >> 9;          // 0 = src, 1 = dst
    const int r0 = rb * 32;
    const float* W = (sd ? Wdst : Wsrc) + h * (IN_DIM_ * UNITS);

    __shared__ float xs[32][132];
    __shared__ float ot[32][65];

    const int tid = threadIdx.x;
    #pragma unroll
    for (int it = 0; it < 4; ++it) {
        int f4 = it * 256 + tid;
        int r = f4 >> 5, c4 = (f4 & 31) << 2;
        *(float4*)&xs[r][c4] = *(const float4*)&feat[(r0 + r) * IN_DIM_ + c4];
    }
    __syncthreads();

    const int tx = tid & 15, ty = tid >> 4;
    const float4 av = *(const float4*)&a[h*64 + tx*4];
    float acc[2][4] = {{0.f,0.f,0.f,0.f},{0.f,0.f,0.f,0.f}};
    for (int k4 = 0; k4 < 128; k4 += 4) {
        float4 x0 = *(const float4*)&xs[ty*2+0][k4];
        float4 x1 = *(const float4*)&xs[ty*2+1][k4];
        float4 w0 = *(const float4*)&W[(k4+0) * UNITS + tx*4];
        float4 w1 = *(const float4*)&W[(k4+1) * UNITS + tx*4];
        float4 w2 = *(const float4*)&W[(k4+2) * UNITS + tx*4];
        float4 w3 = *(const float4*)&W[(k4+3) * UNITS + tx*4];
#define K1STEP(xc, wq) \
        acc[0][0]=fmaf(x0.xc,wq.x,acc[0][0]); acc[0][1]=fmaf(x0.xc,wq.y,acc[0][1]); \
        acc[0][2]=fmaf(x0.xc,wq.z,acc[0][2]); acc[0][3]=fmaf(x0.xc,wq.w,acc[0][3]); \
        acc[1][0]=fmaf(x1.xc,wq.x,acc[1][0]); acc[1][1]=fmaf(x1.xc,wq.y,acc[1][1]); \
        acc[1][2]=fmaf(x1.xc,wq.z,acc[1][2]); acc[1][3]=fmaf(x1.xc,wq.w,acc[1][3]);
        K1STEP(x, w0) K1STEP(y, w1) K1STEP(z, w2) K1STEP(w, w3)
#undef K1STEP
    }
    // a-dot from registers: partial over this thread's 4 cols, reduce over tx group
    float p0 = acc[0][0]*av.x + acc[0][1]*av.y + acc[0][2]*av.z + acc[0][3]*av.w;
    float p1 = acc[1][0]*av.x + acc[1][1]*av.y + acc[1][2]*av.z + acc[1][3]*av.w;
    #pragma unroll
    for (int d = 1; d < 16; d <<= 1) {
        p0 += __shfl_xor(p0, d, 64);
        p1 += __shfl_xor(p1, d, 64);
    }
    if (tx == 0) {
        float* AD = sd ? Ad : As;
        AD[h*4096 + r0 + ty*2 + 0] = p0;
        AD[h*4096 + r0 + ty*2 + 1] = p1;
    }
    if (sd == 0) {
        #pragma unroll
        for (int r = 0; r < 2; ++r) {
            float4 v = make_float4(acc[r][0], acc[r][1], acc[r][2], acc[r][3]);
            *(float4*)&hsrc[(h * 4096 + r0 + ty*2 + r) * UNITS + tx*4] = v;
        }
    } else {
        #pragma unroll
        for (int r = 0; r < 2; ++r) {
            #pragma unroll
            for (int c = 0; c < 4; ++c) ot[ty*2 + r][tx*4 + c] = acc[r][c];
        }
        __syncthreads();
        const int bidx = r0 >> 9, jb0 = r0 & 511;
        #pragma unroll
        for (int it = 0; it < 8; ++it) {
            int f = it * 256 + tid;
            int u = f >> 5, jl = f & 31;
            hdstT[(((h*8 + bidx) * 64 + u) << 9) + jb0 + jl] = ot[jl][u];
        }
    }
}

// ---- Kernel 2: wave = (row-pair, head). Dual-row fused serial phases. ----
__global__ __launch_bounds__(256, 8) void gat_k2(
    const float* __restrict__ hsrc, const float* __restrict__ hdstT,
    const float* __restrict__ As_g, const float* __restrict__ Ad_g,
    const int* __restrict__ adj, const float* __restrict__ a_g,
    float* __restrict__ out)
{
    __shared__ float zAll[4][2][64];
    __shared__ int   jAll[4][2][64];

    const int tid = threadIdx.x;
    const int w = tid >> 6, lane = tid & 63;
    float* z0 = zAll[w][0]; float* z1 = zAll[w][1];
    int*   j0 = jAll[w][0]; int*   j1 = jAll[w][1];

    // XCD-bijective swizzle: 2048 blocks, each XCD gets 256 consecutive work-ids
    const int bid = blockIdx.x;
    const int swz = (bid & 7) * 256 + (bid >> 3);
    const int wid = swz * 4 + w;          // 0..8191
    const int slice = wid >> 8;           // h*8 + b   (32 slices)
    const int rp    = wid & 255;          // row-pair within slice
    const int h = slice >> 3, b = slice & 7;
    const int i0 = rp * 2;
    const unsigned VALIDU = mapu(-5e7f);

    const float* dbase = hdstT + (slice << 15);    // [64][512] fp32 slice

    const float aqreg = 0.05f * a_g[h*64 + lane];  // 0.4/8 * a
    const int grow0 = b*512 + i0;
    const float sreg0 = hsrc[((h*4096 + grow0) << 6) + lane];
    const float sreg1 = hsrc[((h*4096 + grow0 + 1) << 6) + lane];
    const float Asi0 = As_g[h*4096 + grow0];
    const float Asi1 = As_g[h*4096 + grow0 + 1];

    float acc0[8] = {0,0,0,0,0,0,0,0};
    float acc1[8] = {0,0,0,0,0,0,0,0};
    #pragma unroll 8
    for (int u = 0; u < 64; ++u) {
        const float4 d0 = *(const float4*)&dbase[(u << 9) + (lane << 2)];
        const float4 d1 = *(const float4*)&dbase[(u << 9) + 256 + (lane << 2)];
        const float su0 = readlane_f(sreg0, u);
        const float su1 = readlane_f(sreg1, u);
        const float qu  = readlane_f(aqreg, u);
        acc0[0]=fmaf(qu,fabsf(su0+d0.x),acc0[0]); acc0[1]=fmaf(qu,fabsf(su0+d0.y),acc0[1]);
        acc0[2]=fmaf(qu,fabsf(su0+d0.z),acc0[2]); acc0[3]=fmaf(qu,fabsf(su0+d0.w),acc0[3]);
        acc0[4]=fmaf(qu,fabsf(su0+d1.x),acc0[4]); acc0[5]=fmaf(qu,fabsf(su0+d1.y),acc0[5]);
        acc0[6]=fmaf(qu,fabsf(su0+d1.z),acc0[6]); acc0[7]=fmaf(qu,fabsf(su0+d1.w),acc0[7]);
        acc1[0]=fmaf(qu,fabsf(su1+d0.x),acc1[0]); acc1[1]=fmaf(qu,fabsf(su1+d0.y),acc1[1]);
        acc1[2]=fmaf(qu,fabsf(su1+d0.z),acc1[2]); acc1[3]=fmaf(qu,fabsf(su1+d0.w),acc1[3]);
        acc1[4]=fmaf(qu,fabsf(su1+d1.x),acc1[4]); acc1[5]=fmaf(qu,fabsf(su1+d1.y),acc1[5]);
        acc1[6]=fmaf(qu,fabsf(su1+d1.z),acc1[6]); acc1[7]=fmaf(qu,fabsf(su1+d1.w),acc1[7]);
    }
    const float4 ad0 = *(const float4*)&Ad_g[h*4096 + b*512 + (lane << 2)];
    const float4 ad1 = *(const float4*)&Ad_g[h*4096 + b*512 + 256 + (lane << 2)];
    const int4 av0 = *(const int4*)&adj[(grow0 << 9) + (lane << 2)];
    const int4 av1 = *(const int4*)&adj[(grow0 << 9) + 256 + (lane << 2)];
    const int4 bv0 = *(const int4*)&adj[((grow0 + 1) << 9) + (lane << 2)];
    const int4 bv1 = *(const int4*)&adj[((grow0 + 1) << 9) + 256 + (lane << 2)];

    // build keys for both rows (scores live only as monotone uint keys)
    unsigned ux0[8], ux1[8];
    {
        const float advk[8] = {ad0.x,ad0.y,ad0.z,ad0.w,ad1.x,ad1.y,ad1.z,ad1.w};
        const int   a0k[8]  = {av0.x,av0.y,av0.z,av0.w,av1.x,av1.y,av1.z,av1.w};
        const int   a1k[8]  = {bv0.x,bv0.y,bv0.z,bv0.w,bv1.x,bv1.y,bv1.z,bv1.w};
        #pragma unroll
        for (int k = 0; k < 8; ++k) {
            int j = ((k >> 2) << 8) + (lane << 2) + (k & 3);
            float s0 = acc0[k] + 0.075f * (Asi0 + advk[k]);
            float s1 = acc1[k] + 0.075f * (Asi1 + advk[k]);
            ux0[k] = mapu((a0k[k] > 0 || j == i0)     ? s0 : NEGV);
            ux1[k] = mapu((a1k[k] > 0 || j == i0 + 1) ? s1 : NEGV);
        }
    }
    // dual radix descent (fused for ILP)
    unsigned p0 = 0u, p1 = 0u;
    bool done0 = false, done1 = false;
    for (int bit = 31; bit >= 0 && !(done0 && done1); --bit) {
        if (!done0) {
            unsigned T = p0 | (1u << bit);
            int c = 0;
            #pragma unroll
            for (int k = 0; k < 8; ++k) c += __popcll(__ballot(ux0[k] >= T));
            if (c >= TOPK) { p0 = T; if (c == TOPK) done0 = true; }
        }
        if (!done1) {
            unsigned T = p1 | (1u << bit);
            int c = 0;
            #pragma unroll
            for (int k = 0; k < 8; ++k) c += __popcll(__ballot(ux1[k] >= T));
            if (c >= TOPK) { p1 = T; if (c == TOPK) done1 = true; }
        }
    }
    // dual compaction into per-wave LDS (tempered scores ×2)
    int cnt0 = 0, cnt1 = 0;
    #pragma unroll
    for (int k = 0; k < 8; ++k) {
        int j = ((k >> 2) << 8) + (lane << 2) + (k & 3);
        bool s0 = (ux0[k] >= p0) && (ux0[k] > VALIDU);
        bool s1 = (ux1[k] >= p1) && (ux1[k] > VALIDU);
        unsigned long long m0 = __ballot(s0);
        unsigned long long m1 = __ballot(s1);
        if (s0) { int pos = cnt0 + mbcnt64(m0); if (pos < 64) { z0[pos] = 2.f * unmapu(ux0[k]); j0[pos] = j; } }
        if (s1) { int pos = cnt1 + mbcnt64(m1); if (pos < 64) { z1[pos] = 2.f * unmapu(ux1[k]); j1[pos] = j; } }
        cnt0 += __popcll(m0); cnt1 += __popcll(m1);
    }
    if (cnt0 > 64) cnt0 = 64;
    if (cnt1 > 64) cnt1 = 64;
    // per-lane survivor registers
    float zl0 = z0[lane], zl1 = z1[lane];
    int   jl0 = j0[lane] & 511, jl1 = j1[lane] & 511;
    bool act0 = lane < cnt0, act1 = lane < cnt1;
    if (!act0) { zl0 = 0.f; jl0 = 0; }
    if (!act1) { zl1 = 0.f; jl1 = 0; }
    // dual Michelot fixed-point (exact sparsemax tau)
    float tau0 = 0.f, tau1 = 0.f;
    {
        unsigned long long am0 = __ballot(act0), am1 = __ballot(act1);
        bool cur0 = act0, cur1 = act1;
        bool cv0 = false, cv1 = false;
        for (int it = 0; it < 64 && !(cv0 && cv1); ++it) {
            float s0 = cur0 ? zl0 : 0.f;
            float s1 = cur1 ? zl1 : 0.f;
            #pragma unroll
            for (int d = 1; d < 64; d <<= 1) {
                s0 += __shfl_xor(s0, d, 64);
                s1 += __shfl_xor(s1, d, 64);
            }
            if (!cv0) {
                tau0 = (s0 - 1.0f) / (float)__popcll(am0);
                bool na = cur0 && (zl0 > tau0);
                unsigned long long nm = __ballot(na);
                if (nm == am0 || nm == 0ull) cv0 = true; else { am0 = nm; cur0 = na; }
            }
            if (!cv1) {
                tau1 = (s1 - 1.0f) / (float)__popcll(am1);
                bool na = cur1 && (zl1 > tau1);
                unsigned long long nm = __ballot(na);
                if (nm == am1 || nm == 0ull) cv1 = true; else { am1 = nm; cur1 = na; }
            }
        }
    }
    // dual sharpen + denom
    float wv0 = fmaxf(zl0 - tau0, 0.f) + 1e-9f;
    float wv1 = fmaxf(zl1 - tau1, 0.f) + 1e-9f;
    float pl0 = act0 ? wv0 * wv0 : 0.f;
    float pl1 = act1 ? wv1 * wv1 : 0.f;
    float ds0 = pl0, ds1 = pl1;
    #pragma unroll
    for (int d = 1; d < 64; d <<= 1) {
        ds0 += __shfl_xor(ds0, d, 64);
        ds1 += __shfl_xor(ds1, d, 64);
    }
    const float w0l = pl0 * (1.0f / (ds0 + 1e-9f + (float)(512 - cnt0) * 1e-18f));
    const float w1l = pl1 * (1.0f / (ds1 + 1e-9f + (float)(512 - cnt1) * 1e-18f));
    // dual gather: 64 loads in flight
    const float* hb = hsrc + ((h*4096 + b*512) << 6) + lane;
    float oa0 = 0.f, oa1 = 0.f;
    #pragma unroll
    for (int t = 0; t < TOPK; ++t) {
        float wt0 = readlane_f(w0l, t);
        float wt1 = readlane_f(w1l, t);
        int   jt0 = __builtin_amdgcn_readlane(jl0, t);
        int   jt1 = __builtin_amdgcn_readlane(jl1, t);
        oa0 = fmaf(wt0, hb[jt0 << 6], oa0);
        oa1 = fmaf(wt1, hb[jt1 << 6], oa1);
    }
    for (int t = TOPK; t < cnt0; ++t) {   // rare tie overflow
        float wt = readlane_f(w0l, t);
        int   jt = __builtin_amdgcn_readlane(jl0, t);
        oa0 = fmaf(wt, hb[jt << 6], oa0);
    }
    for (int t = TOPK; t < cnt1; ++t) {
        float wt = readlane_f(w1l, t);
        int   jt = __builtin_amdgcn_readlane(jl1, t);
        oa1 = fmaf(wt, hb[jt << 6], oa1);
    }
    atomicAdd(&out[((b*512 + i0)     << 6) + lane], 0.25f * oa0);
    atomicAdd(&out[((b*512 + i0 + 1) << 6) + lane], 0.25f * oa1);
}

extern "C" void kernel_launch(void* const* d_in, const int* in_sizes, int n_in,
                              void* d_out, int out_size, void* d_ws, size_t ws_size,
                              hipStream_t stream) {
    const float* feat = (const float*)d_in[0];
    const int*   adj  = (const int*)d_in[1];
    const float* Wsrc = (const float*)d_in[2];
    const float* Wdst = (const float*)d_in[3];
    const float* a    = (const float*)d_in[4];
    float* out = (float*)d_out;
    float* ws  = (float*)d_ws;
    float* hsrc  = ws;                 // 4*4096*64   = 1048576 floats
    float* hdstT = ws + 1048576;       // 4*8*64*512  = 1048576 floats
    float* As    = ws + 2097152;       // 4*4096
    float* Ad    = ws + 2113536;       // 4*4096

    hipMemsetAsync(d_out, 0, (size_t)out_size * sizeof(float), stream);
    gat_k1<<<1024, 256, 0, stream>>>(feat, Wsrc, Wdst, a, hsrc, hdstT, As, Ad);
    gat_k2<<<2048, 256, 0, stream>>>(hsrc, hdstT, As, Ad, adj, a, out);
}

// Round 14
// 152.163 us; speedup vs baseline: 1.2819x; 1.0051x over previous
//
#include <hip/hip_runtime.h>
#include <hip/hip_bf16.h>

#define HEADS 4
#define UNITS 64
#define IN_DIM_ 128
#define NN 512
#define TOPK 32
#define NEGV -1e9f

__device__ __forceinline__ float readlane_f(float v, int l) {
    return __int_as_float(__builtin_amdgcn_readlane(__float_as_int(v), l));
}
__device__ __forceinline__ unsigned mapu(float x) {
    unsigned b = __float_as_uint(x);
    return b ^ ((unsigned)((int)b >> 31) | 0x80000000u);
}
__device__ __forceinline__ float unmapu(unsigned u) {
    unsigned b = ((int)u < 0) ? (u ^ 0x80000000u) : ~u;
    return __uint_as_float(b);
}
__device__ __forceinline__ int mbcnt64(unsigned long long m) {
    return __builtin_amdgcn_mbcnt_hi((unsigned)(m >> 32),
           __builtin_amdgcn_mbcnt_lo((unsigned)(m & 0xFFFFFFFFull), 0u));
}

// -------- Kernel 1: projections + transposed copy + a-dot scalars ----------
// W direct from L2 with unroll-4 load-ahead (16 loads in flight); sd==0
// blocks also zero `out` so no separate memset dispatch is needed.
__global__ __launch_bounds__(256) void gat_k1(
    const float* __restrict__ feat, const float* __restrict__ Wsrc,
    const float* __restrict__ Wdst, const float* __restrict__ a,
    float* __restrict__ hsrc, float* __restrict__ hdstT,
    float* __restrict__ As, float* __restrict__ Ad, float* __restrict__ out)
{
    const int bx = blockIdx.x;
    const int rb = bx & 127;         // 128 row-blocks of 32 rows (4096 rows)
    const int h  = (bx >> 7) & 3;
    const int sd = bx >> 9;          // 0 = src, 1 = dst
    const int r0 = rb * 32;
    const float* W = (sd ? Wdst : Wsrc) + h * (IN_DIM_ * UNITS);

    __shared__ float xs[32][132];
    __shared__ float ot[32][65];

    const int tid = threadIdx.x;
    if (sd == 0) {                   // zero out (1 MB total over 512 blocks)
        ((float2*)out)[(bx << 8) + tid] = make_float2(0.f, 0.f);
    }
    #pragma unroll
    for (int it = 0; it < 4; ++it) {
        int f4 = it * 256 + tid;
        int r = f4 >> 5, c4 = (f4 & 31) << 2;
        *(float4*)&xs[r][c4] = *(const float4*)&feat[(r0 + r) * IN_DIM_ + c4];
    }
    __syncthreads();

    const int tx = tid & 15, ty = tid >> 4;
    const float4 av = *(const float4*)&a[h*64 + tx*4];
    float acc[2][4] = {{0.f,0.f,0.f,0.f},{0.f,0.f,0.f,0.f}};
    #pragma unroll 4
    for (int k4 = 0; k4 < 128; k4 += 4) {
        float4 x0 = *(const float4*)&xs[ty*2+0][k4];
        float4 x1 = *(const float4*)&xs[ty*2+1][k4];
        float4 w0 = *(const float4*)&W[(k4+0) * UNITS + tx*4];
        float4 w1 = *(const float4*)&W[(k4+1) * UNITS + tx*4];
        float4 w2 = *(const float4*)&W[(k4+2) * UNITS + tx*4];
        float4 w3 = *(const float4*)&W[(k4+3) * UNITS + tx*4];
#define K1STEP(xc, wq) \
        acc[0][0]=fmaf(x0.xc,wq.x,acc[0][0]); acc[0][1]=fmaf(x0.xc,wq.y,acc[0][1]); \
        acc[0][2]=fmaf(x0.xc,wq.z,acc[0][2]); acc[0][3]=fmaf(x0.xc,wq.w,acc[0][3]); \
        acc[1][0]=fmaf(x1.xc,wq.x,acc[1][0]); acc[1][1]=fmaf(x1.xc,wq.y,acc[1][1]); \
        acc[1][2]=fmaf(x1.xc,wq.z,acc[1][2]); acc[1][3]=fmaf(x1.xc,wq.w,acc[1][3]);
        K1STEP(x, w0) K1STEP(y, w1) K1STEP(z, w2) K1STEP(w, w3)
#undef K1STEP
    }
    // a-dot from registers: partial over this thread's 4 cols, reduce over tx group
    float p0 = acc[0][0]*av.x + acc[0][1]*av.y + acc[0][2]*av.z + acc[0][3]*av.w;
    float p1 = acc[1][0]*av.x + acc[1][1]*av.y + acc[1][2]*av.z + acc[1][3]*av.w;
    #pragma unroll
    for (int d = 1; d < 16; d <<= 1) {
        p0 += __shfl_xor(p0, d, 64);
        p1 += __shfl_xor(p1, d, 64);
    }
    if (tx == 0) {
        float* AD = sd ? Ad : As;
        AD[h*4096 + r0 + ty*2 + 0] = p0;
        AD[h*4096 + r0 + ty*2 + 1] = p1;
    }
    if (sd == 0) {
        #pragma unroll
        for (int r = 0; r < 2; ++r) {
            float4 v = make_float4(acc[r][0], acc[r][1], acc[r][2], acc[r][3]);
            *(float4*)&hsrc[(h * 4096 + r0 + ty*2 + r) * UNITS + tx*4] = v;
        }
    } else {
        #pragma unroll
        for (int r = 0; r < 2; ++r) {
            #pragma unroll
            for (int c = 0; c < 4; ++c) ot[ty*2 + r][tx*4 + c] = acc[r][c];
        }
        __syncthreads();
        const int bidx = r0 >> 9, jb0 = r0 & 511;
        #pragma unroll
        for (int it = 0; it < 8; ++it) {
            int f = it * 256 + tid;
            int u = f >> 5, jl = f & 31;
            hdstT[(((h*8 + bidx) * 64 + u) << 9) + jb0 + jl] = ot[jl][u];
        }
    }
}

// ---- Kernel 2: wave = (row-pair, head). Dual-row fused serial phases. ----
__global__ __launch_bounds__(256, 8) void gat_k2(
    const float* __restrict__ hsrc, const float* __restrict__ hdstT,
    const float* __restrict__ As_g, const float* __restrict__ Ad_g,
    const int* __restrict__ adj, const float* __restrict__ a_g,
    float* __restrict__ out)
{
    __shared__ float zAll[4][2][64];
    __shared__ int   jAll[4][2][64];

    const int tid = threadIdx.x;
    const int w = tid >> 6, lane = tid & 63;
    float* z0 = zAll[w][0]; float* z1 = zAll[w][1];
    int*   j0 = jAll[w][0]; int*   j1 = jAll[w][1];

    // XCD-bijective swizzle: 2048 blocks, each XCD gets 256 consecutive work-ids
    const int bid = blockIdx.x;
    const int swz = (bid & 7) * 256 + (bid >> 3);
    const int wid = swz * 4 + w;          // 0..8191
    const int slice = wid >> 8;           // h*8 + b   (32 slices)
    const int rp    = wid & 255;          // row-pair within slice
    const int h = slice >> 3, b = slice & 7;
    const int i0 = rp * 2;
    const unsigned VALIDU = mapu(-5e7f);

    const float* dbase = hdstT + (slice << 15);    // [64][512] fp32 slice

    const float aqreg = 0.05f * a_g[h*64 + lane];  // 0.4/8 * a
    const int grow0 = b*512 + i0;
    const float sreg0 = hsrc[((h*4096 + grow0) << 6) + lane];
    const float sreg1 = hsrc[((h*4096 + grow0 + 1) << 6) + lane];
    const float Asi0 = As_g[h*4096 + grow0];
    const float Asi1 = As_g[h*4096 + grow0 + 1];

    float acc0[8] = {0,0,0,0,0,0,0,0};
    float acc1[8] = {0,0,0,0,0,0,0,0};
    #pragma unroll 8
    for (int u = 0; u < 64; ++u) {
        const float4 d0 = *(const float4*)&dbase[(u << 9) + (lane << 2)];
        const float4 d1 = *(const float4*)&dbase[(u << 9) + 256 + (lane << 2)];
        const float su0 = readlane_f(sreg0, u);
        const float su1 = readlane_f(sreg1, u);
        const float qu  = readlane_f(aqreg, u);
        acc0[0]=fmaf(qu,fabsf(su0+d0.x),acc0[0]); acc0[1]=fmaf(qu,fabsf(su0+d0.y),acc0[1]);
        acc0[2]=fmaf(qu,fabsf(su0+d0.z),acc0[2]); acc0[3]=fmaf(qu,fabsf(su0+d0.w),acc0[3]);
        acc0[4]=fmaf(qu,fabsf(su0+d1.x),acc0[4]); acc0[5]=fmaf(qu,fabsf(su0+d1.y),acc0[5]);
        acc0[6]=fmaf(qu,fabsf(su0+d1.z),acc0[6]); acc0[7]=fmaf(qu,fabsf(su0+d1.w),acc0[7]);
        acc1[0]=fmaf(qu,fabsf(su1+d0.x),acc1[0]); acc1[1]=fmaf(qu,fabsf(su1+d0.y),acc1[1]);
        acc1[2]=fmaf(qu,fabsf(su1+d0.z),acc1[2]); acc1[3]=fmaf(qu,fabsf(su1+d0.w),acc1[3]);
        acc1[4]=fmaf(qu,fabsf(su1+d1.x),acc1[4]); acc1[5]=fmaf(qu,fabsf(su1+d1.y),acc1[5]);
        acc1[6]=fmaf(qu,fabsf(su1+d1.z),acc1[6]); acc1[7]=fmaf(qu,fabsf(su1+d1.w),acc1[7]);
    }
    const float4 ad0 = *(const float4*)&Ad_g[h*4096 + b*512 + (lane << 2)];
    const float4 ad1 = *(const float4*)&Ad_g[h*4096 + b*512 + 256 + (lane << 2)];
    const int4 av0 = *(const int4*)&adj[(grow0 << 9) + (lane << 2)];
    const int4 av1 = *(const int4*)&adj[(grow0 << 9) + 256 + (lane << 2)];
    const int4 bv0 = *(const int4*)&adj[((grow0 + 1) << 9) + (lane << 2)];
    const int4 bv1 = *(const int4*)&adj[((grow0 + 1) << 9) + 256 + (lane << 2)];

    // build keys for both rows (scores live only as monotone uint keys)
    unsigned ux0[8], ux1[8];
    {
        const float advk[8] = {ad0.x,ad0.y,ad0.z,ad0.w,ad1.x,ad1.y,ad1.z,ad1.w};
        const int   a0k[8]  = {av0.x,av0.y,av0.z,av0.w,av1.x,av1.y,av1.z,av1.w};
        const int   a1k[8]  = {bv0.x,bv0.y,bv0.z,bv0.w,bv1.x,bv1.y,bv1.z,bv1.w};
        #pragma unroll
        for (int k = 0; k < 8; ++k) {
            int j = ((k >> 2) << 8) + (lane << 2) + (k & 3);
            float s0 = acc0[k] + 0.075f * (Asi0 + advk[k]);
            float s1 = acc1[k] + 0.075f * (Asi1 + advk[k]);
            ux0[k] = mapu((a0k[k] > 0 || j == i0)     ? s0 : NEGV);
            ux1[k] = mapu((a1k[k] > 0 || j == i0 + 1) ? s1 : NEGV);
        }
    }
    // dual radix descent (fused for ILP)
    unsigned p0 = 0u, p1 = 0u;
    bool done0 = false, done1 = false;
    for (int bit = 31; bit >= 0 && !(done0 && done1); --bit) {
        if (!done0) {
            unsigned T = p0 | (1u << bit);
            int c = 0;
            #pragma unroll
            for (int k = 0; k < 8; ++k) c += __popcll(__ballot(ux0[k] >= T));
            if (c >= TOPK) { p0 = T; if (c == TOPK) done0 = true; }
        }
        if (!done1) {
            unsigned T = p1 | (1u << bit);
            int c = 0;
            #pragma unroll
            for (int k = 0; k < 8; ++k) c += __popcll(__ballot(ux1[k] >= T));
            if (c >= TOPK) { p1 = T; if (c == TOPK) done1 = true; }
        }
    }
    // dual compaction into per-wave LDS (tempered scores ×2)
    int cnt0 = 0, cnt1 = 0;
    #pragma unroll
    for (int k = 0; k < 8; ++k) {
        int j = ((k >> 2) << 8) + (lane << 2) + (k & 3);
        bool s0 = (ux0[k] >= p0) && (ux0[k] > VALIDU);
        bool s1 = (ux1[k] >= p1) && (ux1[k] > VALIDU);
        unsigned long long m0 = __ballot(s0);
        unsigned long long m1 = __ballot(s1);
        if (s0) { int pos = cnt0 + mbcnt64(m0); if (pos < 64) { z0[pos] = 2.f * unmapu(ux0[k]); j0[pos] = j; } }
        if (s1) { int pos = cnt1 + mbcnt64(m1); if (pos < 64) { z1[pos] = 2.f * unmapu(ux1[k]); j1[pos] = j; } }
        cnt0 += __popcll(m0); cnt1 += __popcll(m1);
    }
    if (cnt0 > 64) cnt0 = 64;
    if (cnt1 > 64) cnt1 = 64;
    // per-lane survivor registers
    float zl0 = z0[lane], zl1 = z1[lane];
    int   jl0 = j0[lane] & 511, jl1 = j1[lane] & 511;
    bool act0 = lane < cnt0, act1 = lane < cnt1;
    if (!act0) { zl0 = 0.f; jl0 = 0; }
    if (!act1) { zl1 = 0.f; jl1 = 0; }
    // dual Michelot fixed-point (exact sparsemax tau)
    float tau0 = 0.f, tau1 = 0.f;
    {
        unsigned long long am0 = __ballot(act0), am1 = __ballot(act1);
        bool cur0 = act0, cur1 = act1;
        bool cv0 = false, cv1 = false;
        for (int it = 0; it < 64 && !(cv0 && cv1); ++it) {
            float s0 = cur0 ? zl0 : 0.f;
            float s1 = cur1 ? zl1 : 0.f;
            #pragma unroll
            for (int d = 1; d < 64; d <<= 1) {
                s0 += __shfl_xor(s0, d, 64);
                s1 += __shfl_xor(s1, d, 64);
            }
            if (!cv0) {
                tau0 = (s0 - 1.0f) / (float)__popcll(am0);
                bool na = cur0 && (zl0 > tau0);
                unsigned long long nm = __ballot(na);
                if (nm == am0 || nm == 0ull) cv0 = true; else { am0 = nm; cur0 = na; }
            }
            if (!cv1) {
                tau1 = (s1 - 1.0f) / (float)__popcll(am1);
                bool na = cur1 && (zl1 > tau1);
                unsigned long long nm = __ballot(na);
                if (nm == am1 || nm == 0ull) cv1 = true; else { am1 = nm; cur1 = na; }
            }
        }
    }
    // dual sharpen + denom
    float wv0 = fmaxf(zl0 - tau0, 0.f) + 1e-9f;
    float wv1 = fmaxf(zl1 - tau1, 0.f) + 1e-9f;
    float pl0 = act0 ? wv0 * wv0 : 0.f;
    float pl1 = act1 ? wv1 * wv1 : 0.f;
    float ds0 = pl0, ds1 = pl1;
    #pragma unroll
    for (int d = 1; d < 64; d <<= 1) {
        ds0 += __shfl_xor(ds0, d, 64);
        ds1 += __shfl_xor(ds1, d, 64);
    }
    const float w0l = pl0 * (1.0f / (ds0 + 1e-9f + (float)(512 - cnt0) * 1e-18f));
    const float w1l = pl1 * (1.0f / (ds1 + 1e-9f + (float)(512 - cnt1) * 1e-18f));
    // dual gather: 64 loads in flight
    const float* hb = hsrc + ((h*4096 + b*512) << 6) + lane;
    float oa0 = 0.f, oa1 = 0.f;
    #pragma unroll
    for (int t = 0; t < TOPK; ++t) {
        float wt0 = readlane_f(w0l, t);
        float wt1 = readlane_f(w1l, t);
        int   jt0 = __builtin_amdgcn_readlane(jl0, t);
        int   jt1 = __builtin_amdgcn_readlane(jl1, t);
        oa0 = fmaf(wt0, hb[jt0 << 6], oa0);
        oa1 = fmaf(wt1, hb[jt1 << 6], oa1);
    }
    for (int t = TOPK; t < cnt0; ++t) {   // rare tie overflow
        float wt = readlane_f(w0l, t);
        int   jt = __builtin_amdgcn_readlane(jl0, t);
        oa0 = fmaf(wt, hb[jt << 6], oa0);
    }
    for (int t = TOPK; t < cnt1; ++t) {
        float wt = readlane_f(w1l, t);
        int   jt = __builtin_amdgcn_readlane(jl1, t);
        oa1 = fmaf(wt, hb[jt << 6], oa1);
    }
    atomicAdd(&out[((b*512 + i0)     << 6) + lane], 0.25f * oa0);
    atomicAdd(&out[((b*512 + i0 + 1) << 6) + lane], 0.25f * oa1);
}

extern "C" void kernel_launch(void* const* d_in, const int* in_sizes, int n_in,
                              void* d_out, int out_size, void* d_ws, size_t ws_size,
                              hipStream_t stream) {
    const float* feat = (const float*)d_in[0];
    const int*   adj  = (const int*)d_in[1];
    const float* Wsrc = (const float*)d_in[2];
    const float* Wdst = (const float*)d_in[3];
    const float* a    = (const float*)d_in[4];
    float* out = (float*)d_out;
    float* ws  = (float*)d_ws;
    float* hsrc  = ws;                 // 4*4096*64   = 1048576 floats
    float* hdstT = ws + 1048576;       // 4*8*64*512  = 1048576 floats
    float* As    = ws + 2097152;       // 4*4096
    float* Ad    = ws + 2113536;       // 4*4096

    gat_k1<<<1024, 256, 0, stream>>>(feat, Wsrc, Wdst, a, hsrc, hdstT, As, Ad, out);
    gat_k2<<<2048, 256, 0, stream>>>(hsrc, hdstT, As, Ad, adj, a, out);
}

// Round 16
// 145.606 us; speedup vs baseline: 1.3397x; 1.0450x over previous
//
#include <hip/hip_runtime.h>
#include <hip/hip_bf16.h>

#define HEADS 4
#define UNITS 64
#define IN_DIM_ 128
#define NN 512
#define TOPK 32
#define NEGV -1e9f

__device__ __forceinline__ float readlane_f(float v, int l) {
    return __int_as_float(__builtin_amdgcn_readlane(__float_as_int(v), l));
}
__device__ __forceinline__ unsigned mapu(float x) {
    unsigned b = __float_as_uint(x);
    return b ^ ((unsigned)((int)b >> 31) | 0x80000000u);
}
__device__ __forceinline__ float unmapu(unsigned u) {
    unsigned b = ((int)u < 0) ? (u ^ 0x80000000u) : ~u;
    return __uint_as_float(b);
}
__device__ __forceinline__ int mbcnt64(unsigned long long m) {
    return __builtin_amdgcn_mbcnt_hi((unsigned)(m >> 32),
           __builtin_amdgcn_mbcnt_lo((unsigned)(m & 0xFFFFFFFFull), 0u));
}

// -------- Kernel 1: projections + transposed copy + a-dot scalars ----------
// W staged in LDS in two 16KB k-phases (L1-thrash fix, round-9 regression
// isolated); wsh reused as transpose buffer; 32.9 KB LDS -> 4 blocks/CU,
// all 1024 blocks resident in one pass. sd==0 blocks also zero `out`.
__global__ __launch_bounds__(256) void gat_k1(
    const float* __restrict__ feat, const float* __restrict__ Wsrc,
    const float* __restrict__ Wdst, const float* __restrict__ a,
    float* __restrict__ hsrc, float* __restrict__ hdstT,
    float* __restrict__ As, float* __restrict__ Ad, float* __restrict__ out)
{
    const int bx = blockIdx.x;
    const int rb = bx & 127;         // 128 row-blocks of 32 rows (4096 rows)
    const int h  = (bx >> 7) & 3;
    const int sd = bx >> 9;          // 0 = src, 1 = dst
    const int r0 = rb * 32;
    const float* W = (sd ? Wdst : Wsrc) + h * (IN_DIM_ * UNITS);

    __shared__ float xs[32][132];    // 16.9 KB
    __shared__ float wsh[64][64];    // 16 KB: one k-phase of W; reused as ot

    const int tid = threadIdx.x;
    if (sd == 0) {                   // zero out (1 MB total over 512 blocks)
        ((float2*)out)[(bx << 8) + tid] = make_float2(0.f, 0.f);
    }
    #pragma unroll
    for (int it = 0; it < 4; ++it) {
        int f4 = it * 256 + tid;
        int r = f4 >> 5, c4 = (f4 & 31) << 2;
        *(float4*)&xs[r][c4] = *(const float4*)&feat[(r0 + r) * IN_DIM_ + c4];
    }

    const int tx = tid & 15, ty = tid >> 4;
    const float4 av = *(const float4*)&a[h*64 + tx*4];
    float acc[2][4] = {{0.f,0.f,0.f,0.f},{0.f,0.f,0.f,0.f}};

    #pragma unroll
    for (int ph = 0; ph < 2; ++ph) {
        if (ph) __syncthreads();     // previous-phase readers done before restage
        #pragma unroll
        for (int it = 0; it < 4; ++it) {
            int f4 = it * 256 + tid;             // 0..1023 -> 64x16 float4
            int r = f4 >> 4, c4 = (f4 & 15) << 2;
            *(float4*)&wsh[r][c4] = *(const float4*)&W[(ph*64 + r) * UNITS + c4];
        }
        __syncthreads();             // also covers xs staging before first read
        #pragma unroll 4
        for (int k4 = 0; k4 < 64; k4 += 4) {
            float4 x0 = *(const float4*)&xs[ty*2+0][ph*64 + k4];
            float4 x1 = *(const float4*)&xs[ty*2+1][ph*64 + k4];
            float4 w0 = *(const float4*)&wsh[k4+0][tx*4];
            float4 w1 = *(const float4*)&wsh[k4+1][tx*4];
            float4 w2 = *(const float4*)&wsh[k4+2][tx*4];
            float4 w3 = *(const float4*)&wsh[k4+3][tx*4];
#define K1STEP(xc, wq) \
            acc[0][0]=fmaf(x0.xc,wq.x,acc[0][0]); acc[0][1]=fmaf(x0.xc,wq.y,acc[0][1]); \
            acc[0][2]=fmaf(x0.xc,wq.z,acc[0][2]); acc[0][3]=fmaf(x0.xc,wq.w,acc[0][3]); \
            acc[1][0]=fmaf(x1.xc,wq.x,acc[1][0]); acc[1][1]=fmaf(x1.xc,wq.y,acc[1][1]); \
            acc[1][2]=fmaf(x1.xc,wq.z,acc[1][2]); acc[1][3]=fmaf(x1.xc,wq.w,acc[1][3]);
            K1STEP(x, w0) K1STEP(y, w1) K1STEP(z, w2) K1STEP(w, w3)
#undef K1STEP
        }
    }
    // a-dot from registers: partial over this thread's 4 cols, reduce over tx group
    float p0 = acc[0][0]*av.x + acc[0][1]*av.y + acc[0][2]*av.z + acc[0][3]*av.w;
    float p1 = acc[1][0]*av.x + acc[1][1]*av.y + acc[1][2]*av.z + acc[1][3]*av.w;
    #pragma unroll
    for (int d = 1; d < 16; d <<= 1) {
        p0 += __shfl_xor(p0, d, 64);
        p1 += __shfl_xor(p1, d, 64);
    }
    if (tx == 0) {
        float* AD = sd ? Ad : As;
        AD[h*4096 + r0 + ty*2 + 0] = p0;
        AD[h*4096 + r0 + ty*2 + 1] = p1;
    }
    if (sd == 0) {
        #pragma unroll
        for (int r = 0; r < 2; ++r) {
            float4 v = make_float4(acc[r][0], acc[r][1], acc[r][2], acc[r][3]);
            *(float4*)&hsrc[(h * 4096 + r0 + ty*2 + r) * UNITS + tx*4] = v;
        }
    } else {
        __syncthreads();             // all waves done reading wsh
        float (*ot)[65] = (float(*)[65])wsh;   // 8.3 KB <= 16 KB, reuse
        #pragma unroll
        for (int r = 0; r < 2; ++r) {
            #pragma unroll
            for (int c = 0; c < 4; ++c) ot[ty*2 + r][tx*4 + c] = acc[r][c];
        }
        __syncthreads();
        const int bidx = r0 >> 9, jb0 = r0 & 511;
        #pragma unroll
        for (int it = 0; it < 8; ++it) {
            int f = it * 256 + tid;
            int u = f >> 5, jl = f & 31;
            hdstT[(((h*8 + bidx) * 64 + u) << 9) + jb0 + jl] = ot[jl][u];
        }
    }
}

// ---- Kernel 2: wave = (row-pair, head). Dual-row fused serial phases. ----
__global__ __launch_bounds__(256, 8) void gat_k2(
    const float* __restrict__ hsrc, const float* __restrict__ hdstT,
    const float* __restrict__ As_g, const float* __restrict__ Ad_g,
    const int* __restrict__ adj, const float* __restrict__ a_g,
    float* __restrict__ out)
{
    __shared__ float zAll[4][2][64];
    __shared__ int   jAll[4][2][64];

    const int tid = threadIdx.x;
    const int w = tid >> 6, lane = tid & 63;
    float* z0 = zAll[w][0]; float* z1 = zAll[w][1];
    int*   j0 = jAll[w][0]; int*   j1 = jAll[w][1];

    // XCD-bijective swizzle: 2048 blocks, each XCD gets 256 consecutive work-ids
    const int bid = blockIdx.x;
    const int swz = (bid & 7) * 256 + (bid >> 3);
    const int wid = swz * 4 + w;          // 0..8191
    const int slice = wid >> 8;           // h*8 + b   (32 slices)
    const int rp    = wid & 255;          // row-pair within slice
    const int h = slice >> 3, b = slice & 7;
    const int i0 = rp * 2;
    const unsigned VALIDU = mapu(-5e7f);

    const float* dbase = hdstT + (slice << 15);    // [64][512] fp32 slice

    const float aqreg = 0.05f * a_g[h*64 + lane];  // 0.4/8 * a
    const int grow0 = b*512 + i0;
    const float sreg0 = hsrc[((h*4096 + grow0) << 6) + lane];
    const float sreg1 = hsrc[((h*4096 + grow0 + 1) << 6) + lane];
    const float Asi0 = As_g[h*4096 + grow0];
    const float Asi1 = As_g[h*4096 + grow0 + 1];

    float acc0[8] = {0,0,0,0,0,0,0,0};
    float acc1[8] = {0,0,0,0,0,0,0,0};
    #pragma unroll 8
    for (int u = 0; u < 64; ++u) {
        const float4 d0 = *(const float4*)&dbase[(u << 9) + (lane << 2)];
        const float4 d1 = *(const float4*)&dbase[(u << 9) + 256 + (lane << 2)];
        const float su0 = readlane_f(sreg0, u);
        const float su1 = readlane_f(sreg1, u);
        const float qu  = readlane_f(aqreg, u);
        acc0[0]=fmaf(qu,fabsf(su0+d0.x),acc0[0]); acc0[1]=fmaf(qu,fabsf(su0+d0.y),acc0[1]);
        acc0[2]=fmaf(qu,fabsf(su0+d0.z),acc0[2]); acc0[3]=fmaf(qu,fabsf(su0+d0.w),acc0[3]);
        acc0[4]=fmaf(qu,fabsf(su0+d1.x),acc0[4]); acc0[5]=fmaf(qu,fabsf(su0+d1.y),acc0[5]);
        acc0[6]=fmaf(qu,fabsf(su0+d1.z),acc0[6]); acc0[7]=fmaf(qu,fabsf(su0+d1.w),acc0[7]);
        acc1[0]=fmaf(qu,fabsf(su1+d0.x),acc1[0]); acc1[1]=fmaf(qu,fabsf(su1+d0.y),acc1[1]);
        acc1[2]=fmaf(qu,fabsf(su1+d0.z),acc1[2]); acc1[3]=fmaf(qu,fabsf(su1+d0.w),acc1[3]);
        acc1[4]=fmaf(qu,fabsf(su1+d1.x),acc1[4]); acc1[5]=fmaf(qu,fabsf(su1+d1.y),acc1[5]);
        acc1[6]=fmaf(qu,fabsf(su1+d1.z),acc1[6]); acc1[7]=fmaf(qu,fabsf(su1+d1.w),acc1[7]);
    }
    const float4 ad0 = *(const float4*)&Ad_g[h*4096 + b*512 + (lane << 2)];
    const float4 ad1 = *(const float4*)&Ad_g[h*4096 + b*512 + 256 + (lane << 2)];
    const int4 av0 = *(const int4*)&adj[(grow0 << 9) + (lane << 2)];
    const int4 av1 = *(const int4*)&adj[(grow0 << 9) + 256 + (lane << 2)];
    const int4 bv0 = *(const int4*)&adj[((grow0 + 1) << 9) + (lane << 2)];
    const int4 bv1 = *(const int4*)&adj[((grow0 + 1) << 9) + 256 + (lane << 2)];

    // build keys for both rows (scores live only as monotone uint keys)
    unsigned ux0[8], ux1[8];
    {
        const float advk[8] = {ad0.x,ad0.y,ad0.z,ad0.w,ad1.x,ad1.y,ad1.z,ad1.w};
        const int   a0k[8]  = {av0.x,av0.y,av0.z,av0.w,av1.x,av1.y,av1.z,av1.w};
        const int   a1k[8]  = {bv0.x,bv0.y,bv0.z,bv0.w,bv1.x,bv1.y,bv1.z,bv1.w};
        #pragma unroll
        for (int k = 0; k < 8; ++k) {
            int j = ((k >> 2) << 8) + (lane << 2) + (k & 3);
            float s0 = acc0[k] + 0.075f * (Asi0 + advk[k]);
            float s1 = acc1[k] + 0.075f * (Asi1 + advk[k]);
            ux0[k] = mapu((a0k[k] > 0 || j == i0)     ? s0 : NEGV);
            ux1[k] = mapu((a1k[k] > 0 || j == i0 + 1) ? s1 : NEGV);
        }
    }
    // dual radix descent (fused for ILP)
    unsigned p0 = 0u, p1 = 0u;
    bool done0 = false, done1 = false;
    for (int bit = 31; bit >= 0 && !(done0 && done1); --bit) {
        if (!done0) {
            unsigned T = p0 | (1u << bit);
            int c = 0;
            #pragma unroll
            for (int k = 0; k < 8; ++k) c += __popcll(__ballot(ux0[k] >= T));
            if (c >= TOPK) { p0 = T; if (c == TOPK) done0 = true; }
        }
        if (!done1) {
            unsigned T = p1 | (1u << bit);
            int c = 0;
            #pragma unroll
            for (int k = 0; k < 8; ++k) c += __popcll(__ballot(ux1[k] >= T));
            if (c >= TOPK) { p1 = T; if (c == TOPK) done1 = true; }
        }
    }
    // dual compaction into per-wave LDS (tempered scores ×2)
    int cnt0 = 0, cnt1 = 0;
    #pragma unroll
    for (int k = 0; k < 8; ++k) {
        int j = ((k >> 2) << 8) + (lane << 2) + (k & 3);
        bool s0 = (ux0[k] >= p0) && (ux0[k] > VALIDU);
        bool s1 = (ux1[k] >= p1) && (ux1[k] > VALIDU);
        unsigned long long m0 = __ballot(s0);
        unsigned long long m1 = __ballot(s1);
        if (s0) { int pos = cnt0 + mbcnt64(m0); if (pos < 64) { z0[pos] = 2.f * unmapu(ux0[k]); j0[pos] = j; } }
        if (s1) { int pos = cnt1 + mbcnt64(m1); if (pos < 64) { z1[pos] = 2.f * unmapu(ux1[k]); j1[pos] = j; } }
        cnt0 += __popcll(m0); cnt1 += __popcll(m1);
    }
    if (cnt0 > 64) cnt0 = 64;
    if (cnt1 > 64) cnt1 = 64;
    // per-lane survivor registers
    float zl0 = z0[lane], zl1 = z1[lane];
    int   jl0 = j0[lane] & 511, jl1 = j1[lane] & 511;
    bool act0 = lane < cnt0, act1 = lane < cnt1;
    if (!act0) { zl0 = 0.f; jl0 = 0; }
    if (!act1) { zl1 = 0.f; jl1 = 0; }
    // dual Michelot fixed-point (exact sparsemax tau)
    float tau0 = 0.f, tau1 = 0.f;
    {
        unsigned long long am0 = __ballot(act0), am1 = __ballot(act1);
        bool cur0 = act0, cur1 = act1;
        bool cv0 = false, cv1 = false;
        for (int it = 0; it < 64 && !(cv0 && cv1); ++it) {
            float s0 = cur0 ? zl0 : 0.f;
            float s1 = cur1 ? zl1 : 0.f;
            #pragma unroll
            for (int d = 1; d < 64; d <<= 1) {
                s0 += __shfl_xor(s0, d, 64);
                s1 += __shfl_xor(s1, d, 64);
            }
            if (!cv0) {
                tau0 = (s0 - 1.0f) / (float)__popcll(am0);
                bool na = cur0 && (zl0 > tau0);
                unsigned long long nm = __ballot(na);
                if (nm == am0 || nm == 0ull) cv0 = true; else { am0 = nm; cur0 = na; }
            }
            if (!cv1) {
                tau1 = (s1 - 1.0f) / (float)__popcll(am1);
                bool na = cur1 && (zl1 > tau1);
                unsigned long long nm = __ballot(na);
                if (nm == am1 || nm == 0ull) cv1 = true; else { am1 = nm; cur1 = na; }
            }
        }
    }
    // dual sharpen + denom
    float wv0 = fmaxf(zl0 - tau0, 0.f) + 1e-9f;
    float wv1 = fmaxf(zl1 - tau1, 0.f) + 1e-9f;
    float pl0 = act0 ? wv0 * wv0 : 0.f;
    float pl1 = act1 ? wv1 * wv1 : 0.f;
    float ds0 = pl0, ds1 = pl1;
    #pragma unroll
    for (int d = 1; d < 64; d <<= 1) {
        ds0 += __shfl_xor(ds0, d, 64);
        ds1 += __shfl_xor(ds1, d, 64);
    }
    const float w0l = pl0 * (1.0f / (ds0 + 1e-9f + (float)(512 - cnt0) * 1e-18f));
    const float w1l = pl1 * (1.0f / (ds1 + 1e-9f + (float)(512 - cnt1) * 1e-18f));
    // dual gather: 64 loads in flight
    const float* hb = hsrc + ((h*4096 + b*512) << 6) + lane;
    float oa0 = 0.f, oa1 = 0.f;
    #pragma unroll
    for (int t = 0; t < TOPK; ++t) {
        float wt0 = readlane_f(w0l, t);
        float wt1 = readlane_f(w1l, t);
        int   jt0 = __builtin_amdgcn_readlane(jl0, t);
        int   jt1 = __builtin_amdgcn_readlane(jl1, t);
        oa0 = fmaf(wt0, hb[jt0 << 6], oa0);
        oa1 = fmaf(wt1, hb[jt1 << 6], oa1);
    }
    for (int t = TOPK; t < cnt0; ++t) {   // rare tie overflow
        float wt = readlane_f(w0l, t);
        int   jt = __builtin_amdgcn_readlane(jl0, t);
        oa0 = fmaf(wt, hb[jt << 6], oa0);
    }
    for (int t = TOPK; t < cnt1; ++t) {
        float wt = readlane_f(w1l, t);
        int   jt = __builtin_amdgcn_readlane(jl1, t);
        oa1 = fmaf(wt, hb[jt << 6], oa1);
    }
    atomicAdd(&out[((b*512 + i0)     << 6) + lane], 0.25f * oa0);
    atomicAdd(&out[((b*512 + i0 + 1) << 6) + lane], 0.25f * oa1);
}

extern "C" void kernel_launch(void* const* d_in, const int* in_sizes, int n_in,
                              void* d_out, int out_size, void* d_ws, size_t ws_size,
                              hipStream_t stream) {
    const float* feat = (const float*)d_in[0];
    const int*   adj  = (const int*)d_in[1];
    const float* Wsrc = (const float*)d_in[2];
    const float* Wdst = (const float*)d_in[3];
    const float* a    = (const float*)d_in[4];
    float* out = (float*)d_out;
    float* ws  = (float*)d_ws;
    float* hsrc  = ws;                 // 4*4096*64   = 1048576 floats
    float* hdstT = ws + 1048576;       // 4*8*64*512  = 1048576 floats
    float* As    = ws + 2097152;       // 4*4096
    float* Ad    = ws + 2113536;       // 4*4096

    gat_k1<<<1024, 256, 0, stream>>>(feat, Wsrc, Wdst, a, hsrc, hdstT, As, Ad, out);
    gat_k2<<<2048, 256, 0, stream>>>(hsrc, hdstT, As, Ad, adj, a, out);
}